// Round 9
// baseline (434.837 us; speedup 1.0000x reference)
//
#include <hip/hip_runtime.h>

// ---------------- constants (problem shape) ----------------
#define NL 2
#define DMODEL 256
#define DI 512
#define FF 1024
#define VV 1024
#define LSEQ 1024
#define RR 16
#define NN 16
#define KCONV 4
#define BTOK 2048   // B * LSEQ
#define EPS 1e-5f

using short8 = __attribute__((ext_vector_type(8))) short;
using float4v = __attribute__((ext_vector_type(4))) float;
typedef unsigned short u16;

__device__ inline float bf2f(u16 u) {
    union { unsigned u; float f; } x; x.u = (unsigned)u << 16; return x.f;
}
__device__ inline u16 f2bf(float f) {
    union { float f; unsigned u; } x; x.f = f;
    unsigned r = x.u + 0x7fffu + ((x.u >> 16) & 1u);
    return (u16)(r >> 16);
}

#if __has_builtin(__builtin_amdgcn_exp2f)
#define EXP2(x) __builtin_amdgcn_exp2f(x)
#else
#define EXP2(x) exp2f(x)
#endif

// ---------------- transpose-all (fp32 weights -> bf16 N-major B^T) ----------------
struct TMat { const float* src; u16* dst; int rows, cols, tile0, tilecols; };
struct TTable { TMat m[24]; int nmat; };

__global__ __launch_bounds__(256) void transpose_kernel(TTable tt) {
    __shared__ u16 tile[32][33];
    int bx = blockIdx.x;
    int j = 0;
    for (int k = 1; k < tt.nmat; ++k) if (bx >= tt.m[k].tile0) j = k;
    TMat mm = tt.m[j];
    int lt = bx - mm.tile0;
    int r0 = (lt / mm.tilecols) * 32, c0 = (lt % mm.tilecols) * 32;
    int tx = threadIdx.x & 31, ty = threadIdx.x >> 5;
    #pragma unroll
    for (int k = 0; k < 4; ++k) {
        int r = r0 + ty + k * 8, c = c0 + tx;
        tile[ty + k * 8][tx] = (r < mm.rows && c < mm.cols) ? f2bf(mm.src[(size_t)r * mm.cols + c]) : (u16)0;
    }
    __syncthreads();
    #pragma unroll
    for (int k = 0; k < 4; ++k) {
        int c = c0 + ty + k * 8, r = r0 + tx;
        if (c < mm.cols && r < mm.rows) mm.dst[(size_t)c * mm.rows + r] = tile[tx][ty + k * 8];
    }
}

// ---------------- LDS-staged MFMA GEMM (m97-style): C = act(A @ Bt^T + bias) --------
// BM=128, BK=32. BN/wave-layout templated. Requires M%128==0, N%BN==0, K%32==0.
// Staging via global_load_lds width16: LDS dest wave-uniform + lane*16 (lane-sequential
// row-major [row][32] tile layout — no padding allowed).
template<int BN, int WR, int WC, int RT, int CT>
__global__ __launch_bounds__(256) void sgemm_kernel(
    const u16* __restrict__ A0, int lda, unsigned long long sA,
    const u16* __restrict__ B0, int ldb, unsigned long long sB,
    const float* __restrict__ bias0, unsigned long long sBias,
    void* __restrict__ C0, int ldc, unsigned long long sC,
    int K, int act, int outfp)
{
    constexpr int BM = 128, BK = 32;
    __shared__ u16 As[BM * BK];
    __shared__ u16 Bs[BN * BK];
    const u16* A = A0 + (size_t)blockIdx.z * sA;
    const u16* Bt = B0 + (size_t)blockIdx.z * sB;
    const float* bias = bias0 ? (bias0 + (size_t)blockIdx.z * sBias) : nullptr;

    const int tid = threadIdx.x, w = tid >> 6, lane = tid & 63;
    const int row0 = blockIdx.y * BM, col0 = blockIdx.x * BN;
    const int wr = w / WC, wc = w % WC;
    const int mi = lane & 15, kq = lane >> 4;
    const int lr = lane >> 2, lc = (lane & 3) * 8;   // staging: lane -> row/col

    float4v acc[RT][CT];
    #pragma unroll
    for (int i = 0; i < RT; ++i)
        #pragma unroll
        for (int j = 0; j < CT; ++j) acc[i][j] = (float4v){0.f, 0.f, 0.f, 0.f};

    for (int kk = 0; kk < K; kk += BK) {
        __syncthreads();
        for (int i = w; i < BM / 16; i += 4) {
            const u16* g = A + (size_t)(row0 + i * 16 + lr) * lda + kk + lc;
            __builtin_amdgcn_global_load_lds(
                (const __attribute__((address_space(1))) void*)g,
                (__attribute__((address_space(3))) void*)(As + i * 16 * BK), 16, 0, 0);
        }
        for (int i = w; i < BN / 16; i += 4) {
            const u16* g = Bt + (size_t)(col0 + i * 16 + lr) * ldb + kk + lc;
            __builtin_amdgcn_global_load_lds(
                (const __attribute__((address_space(1))) void*)g,
                (__attribute__((address_space(3))) void*)(Bs + i * 16 * BK), 16, 0, 0);
        }
        __syncthreads();
        short8 af[RT], bf[CT];
        #pragma unroll
        for (int i = 0; i < RT; ++i)
            af[i] = *(const short8*)(As + (wr * RT * 16 + i * 16 + mi) * BK + kq * 8);
        #pragma unroll
        for (int j = 0; j < CT; ++j)
            bf[j] = *(const short8*)(Bs + (wc * CT * 16 + j * 16 + mi) * BK + kq * 8);
        #pragma unroll
        for (int i = 0; i < RT; ++i)
            #pragma unroll
            for (int j = 0; j < CT; ++j)
                acc[i][j] = __builtin_amdgcn_mfma_f32_16x16x32_bf16(af[i], bf[j], acc[i][j], 0, 0, 0);
    }

    #pragma unroll
    for (int i = 0; i < RT; ++i)
        #pragma unroll
        for (int j = 0; j < CT; ++j) {
            int n = col0 + wc * CT * 16 + j * 16 + mi;
            float bv = bias ? bias[n] : 0.f;
            #pragma unroll
            for (int r = 0; r < 4; ++r) {
                int m = row0 + wr * RT * 16 + i * 16 + kq * 4 + r;
                float v = acc[i][j][r] + bv;
                if (act == 1) v = fmaxf(v, 0.f);
                if (outfp)
                    ((float*)C0)[(size_t)blockIdx.z * sC + (size_t)m * ldc + n] = v;
                else
                    ((u16*)C0)[(size_t)blockIdx.z * sC + (size_t)m * ldc + n] = f2bf(v);
            }
        }
}

// ---------------- generic batched MFMA GEMM (boundary-safe; used for N=48 xdb) ------
__global__ __launch_bounds__(256) void gemm_kernel(
    const u16* __restrict__ A0, int lda, unsigned long long sA,
    const u16* __restrict__ B0, int ldb, unsigned long long sB,
    const float* __restrict__ bias0, unsigned long long sBias,
    void* __restrict__ C0, int ldc, unsigned long long sC,
    int M, int N, int K, int act, int outfp)
{
    const u16* A = A0 + (size_t)blockIdx.z * sA;
    const u16* Bt = B0 + (size_t)blockIdx.z * sB;
    const float* bias = bias0 ? (bias0 + (size_t)blockIdx.z * sBias) : nullptr;

    int tid = threadIdx.x;
    int wv = tid >> 6, lane = tid & 63;
    int row0 = blockIdx.y * 64 + (wv >> 1) * 32;
    int col0 = blockIdx.x * 64 + (wv & 1) * 32;
    int mi = lane & 15, kq = lane >> 4;

    float4v acc[2][2];
    #pragma unroll
    for (int a = 0; a < 2; ++a)
        #pragma unroll
        for (int b = 0; b < 2; ++b) acc[a][b] = (float4v){0.f, 0.f, 0.f, 0.f};
    const short8 zer = {0, 0, 0, 0, 0, 0, 0, 0};

    for (int kk = 0; kk < K; kk += 32) {
        int k = kk + kq * 8;
        bool kv = (k < K);
        short8 af[2], bf[2];
        #pragma unroll
        for (int rt = 0; rt < 2; ++rt) {
            int r = row0 + rt * 16 + mi;
            af[rt] = kv ? *(const short8*)(A + (size_t)r * lda + k) : zer;
        }
        #pragma unroll
        for (int ct = 0; ct < 2; ++ct) {
            int n = col0 + ct * 16 + mi;
            bf[ct] = (kv && n < N) ? *(const short8*)(Bt + (size_t)n * ldb + k) : zer;
        }
        #pragma unroll
        for (int rt = 0; rt < 2; ++rt)
            #pragma unroll
            for (int ct = 0; ct < 2; ++ct)
                acc[rt][ct] = __builtin_amdgcn_mfma_f32_16x16x32_bf16(af[rt], bf[ct], acc[rt][ct], 0, 0, 0);
    }

    #pragma unroll
    for (int rt = 0; rt < 2; ++rt)
        #pragma unroll
        for (int ct = 0; ct < 2; ++ct) {
            int n = col0 + ct * 16 + mi;
            if (n >= N) continue;
            float bv = bias ? bias[n] : 0.f;
            #pragma unroll
            for (int r = 0; r < 4; ++r) {
                int m = row0 + rt * 16 + kq * 4 + r;
                float v = acc[rt][ct][r] + bv;
                if (act == 1) v = fmaxf(v, 0.f);
                if (outfp)
                    ((float*)C0)[(size_t)blockIdx.z * sC + (size_t)m * ldc + n] = v;
                else
                    ((u16*)C0)[(size_t)blockIdx.z * sC + (size_t)m * ldc + n] = f2bf(v);
            }
        }
}

// ---------------- fused delta GEMM (K=16): delta = softplus(xdb[:, :16] @ Wdt + bdt) ----------------
// Writes deltaT and uT = (delta*xc)T in (dir, b, d, t) layout, t contiguous.
__global__ __launch_bounds__(256) void delta_fused_kernel(
    const u16* __restrict__ xdb, const u16* __restrict__ wdtT,
    const float* __restrict__ bdt, const u16* __restrict__ xc,
    u16* __restrict__ deltaT, u16* __restrict__ uT, int layer)
{
    int z = blockIdx.z;   // dir
    const u16* A = xdb + (size_t)z * BTOK * 48;
    const u16* Bt = wdtT + (size_t)z * 512 * 16;
    const float* bias = bdt + (size_t)z * 512;

    int tid = threadIdx.x;
    int wv = tid >> 6, lane = tid & 63;
    int row0 = blockIdx.y * 64 + (wv >> 1) * 32;
    int col0 = blockIdx.x * 64 + (wv & 1) * 32;
    int mi = lane & 15, kq = lane >> 4;

    float4v acc[2][2];
    #pragma unroll
    for (int a = 0; a < 2; ++a)
        #pragma unroll
        for (int b = 0; b < 2; ++b) acc[a][b] = (float4v){0.f, 0.f, 0.f, 0.f};
    const short8 zer = {0, 0, 0, 0, 0, 0, 0, 0};

    int k = kq * 8;
    bool kv = (k < 16);
    short8 af[2], bf[2];
    #pragma unroll
    for (int rt = 0; rt < 2; ++rt) {
        int r = row0 + rt * 16 + mi;
        af[rt] = kv ? *(const short8*)(A + (size_t)r * 48 + k) : zer;
    }
    #pragma unroll
    for (int ct = 0; ct < 2; ++ct) {
        int n = col0 + ct * 16 + mi;
        bf[ct] = kv ? *(const short8*)(Bt + (size_t)n * 16 + k) : zer;
    }
    #pragma unroll
    for (int rt = 0; rt < 2; ++rt)
        #pragma unroll
        for (int ct = 0; ct < 2; ++ct)
            acc[rt][ct] = __builtin_amdgcn_mfma_f32_16x16x32_bf16(af[rt], bf[ct], acc[rt][ct], 0, 0, 0);

    #pragma unroll
    for (int rt = 0; rt < 2; ++rt)
        #pragma unroll
        for (int ct = 0; ct < 2; ++ct) {
            int n = col0 + ct * 16 + mi;
            float bv = bias[n];
            #pragma unroll
            for (int r = 0; r < 4; ++r) {
                int m = row0 + rt * 16 + kq * 4 + r;
                float v = acc[rt][ct][r] + bv;
                v = (v > 20.f) ? v : logf(1.f + __expf(v));   // softplus
                float xcv = bf2f(xc[((size_t)z * BTOK + m) * DI + n]);
                int b = m >> 10, t = m & 1023;
                size_t off = ((size_t)((z * 2 + b) * DI + n)) * LSEQ + t;
                deltaT[off] = f2bf(v);
                uT[off] = f2bf(v * xcv);
            }
        }
}

// ---------------- Bm/Cm transpose: xdb[:, 16:48] -> bcT (slab, 32 rows, 1024 t) ----------------
__global__ __launch_bounds__(256) void bct_kernel(
    const u16* __restrict__ xdb, u16* __restrict__ bcT)
{
    __shared__ u16 tile[32][34];
    int slab = blockIdx.y;
    int t0 = blockIdx.x * 32;
    int tx = threadIdx.x & 31, ty = threadIdx.x >> 5;
    #pragma unroll
    for (int k = 0; k < 4; ++k) {
        int t = t0 + ty + k * 8;
        tile[tx][ty + k * 8] = xdb[(size_t)(slab * 1024 + t) * 48 + 16 + tx];
    }
    __syncthreads();
    #pragma unroll
    for (int k = 0; k < 4; ++k) {
        int col = ty + k * 8;
        bcT[((size_t)(slab * 32 + col)) * LSEQ + t0 + tx] = tile[col][tx];
    }
}

// ---------------- embedding ----------------
__global__ __launch_bounds__(256) void embed_kernel(
    const int* __restrict__ ids, const float* __restrict__ emb,
    const float* __restrict__ pos, u16* __restrict__ x)
{
    int tok = blockIdx.x, d = threadIdx.x;
    int id = ids[tok];
    float v = emb[(size_t)id * DMODEL + d] * 16.0f + pos[(size_t)(tok & (LSEQ - 1)) * DMODEL + d];
    x[(size_t)tok * DMODEL + d] = f2bf(v);
}

// ---------------- depthwise causal / anti-causal conv + SiLU ----------------
__global__ __launch_bounds__(256) void conv_kernel(
    const u16* __restrict__ xz, const float* __restrict__ conv_w,
    const float* __restrict__ conv_b, u16* __restrict__ xc, int layer)
{
    unsigned g = blockIdx.x * 256u + threadIdx.x;   // 2*2*1024*512 total
    int d = g & 511;
    int t = (g >> 9) & 1023;
    int b = (g >> 19) & 1;
    int dir = g >> 20;
    int wbase = ((layer * 2 + dir) * DI + d);
    float acc = conv_b[wbase];
    int colbase = dir * 1024 + d;
    #pragma unroll
    for (int k = 0; k < KCONV; ++k) {
        int ts = dir ? (t + 3 - k) : (t - 3 + k);
        if (ts >= 0 && ts < LSEQ)
            acc += conv_w[wbase * KCONV + k] * bf2f(xz[(size_t)((b << 10) + ts) * 2048 + colbase]);
    }
    float v = acc / (1.f + __expf(-acc));   // silu
    xc[(size_t)(((dir * 2 + b) << 10) + t) * DI + d] = f2bf(v);
}

// ---------------- selective scan: n-outer streaming, coalesced bcT, K-S stitch ----
template<int DIR>
__device__ __forceinline__ void scan_body(
    const u16* __restrict__ deltaT, const u16* __restrict__ uT,
    const u16* __restrict__ bcT, const float* __restrict__ A_log,
    u16* __restrict__ pT, int layer, int slab,
    float* Ps, float* Qs)
{
    const int c = threadIdx.x;   // chunk 0..127
    const int d = blockIdx.x;

    float a2[16];
    const float* al = A_log + (size_t)(((layer * 2 + DIR) * DI + d) * NN);
    #pragma unroll
    for (int n = 0; n < 16; ++n) a2[n] = -__expf(al[n]) * 1.44269504f;   // a*log2(e)

    const size_t tb = ((size_t)(slab * DI + d)) * LSEQ;
    const size_t bcb = (size_t)slab * 32 * LSEQ;
    const int T0 = DIR ? (1016 - 8 * c) : (8 * c);

    short8 dlv = *(const short8*)(deltaT + tb + T0);
    short8 uvv = *(const short8*)(uT + tb + T0);
    float dls[8], uvs[8];
    #pragma unroll
    for (int s = 0; s < 8; ++s) {
        const int idx = DIR ? 7 - s : s;
        dls[s] = bf2f((u16)dlv[idx]);
        uvs[s] = bf2f((u16)uvv[idx]);
    }

    const int base = c * 17;
    #pragma unroll
    for (int n = 0; n < 16; ++n) {
        short8 B8 = *(const short8*)(bcT + bcb + (size_t)n * LSEQ + T0);
        float P = 1.f, Q = 0.f;
        #pragma unroll
        for (int s = 0; s < 8; ++s) {
            const int idx = DIR ? 7 - s : s;
            float dA = EXP2(dls[s] * a2[n]);
            Q = Q * dA + uvs[s] * bf2f((u16)B8[idx]);
            P *= dA;
        }
        Ps[base + n] = P;
        Qs[base + n] = Q;
    }
    __syncthreads();

    for (int off = 1; off < 128; off <<= 1) {
        float np[16], nq[16];
        const bool act = (c >= off);
        if (act) {
            const int nb = (c - off) * 17;
            #pragma unroll
            for (int n = 0; n < 16; ++n) { np[n] = Ps[nb + n]; nq[n] = Qs[nb + n]; }
        }
        __syncthreads();
        if (act) {
            #pragma unroll
            for (int n = 0; n < 16; ++n) {
                float p = Ps[base + n], q = Qs[base + n];
                Qs[base + n] = fmaf(p, nq[n], q);
                Ps[base + n] = p * np[n];
            }
        }
        __syncthreads();
    }

    float pacc[8];
    #pragma unroll
    for (int s = 0; s < 8; ++s) pacc[s] = 0.f;
    const int hb = (c - 1) * 17;
    #pragma unroll
    for (int n = 0; n < 16; ++n) {
        short8 B8 = *(const short8*)(bcT + bcb + (size_t)n * LSEQ + T0);
        short8 C8 = *(const short8*)(bcT + bcb + (size_t)(16 + n) * LSEQ + T0);
        float h = (c == 0) ? 0.f : Qs[hb + n];
        #pragma unroll
        for (int s = 0; s < 8; ++s) {
            const int idx = DIR ? 7 - s : s;
            float dA = EXP2(dls[s] * a2[n]);
            h = h * dA + uvs[s] * bf2f((u16)B8[idx]);
            pacc[s] = fmaf(h, bf2f((u16)C8[idx]), pacc[s]);
        }
    }
    short8 pk;
    #pragma unroll
    for (int s = 0; s < 8; ++s) {
        const int idx = DIR ? 7 - s : s;
        pk[idx] = (short)f2bf(pacc[s]);
    }
    *(short8*)(pT + tb + T0) = pk;
}

__global__ __launch_bounds__(128) void scan_kernel(
    const u16* __restrict__ deltaT, const u16* __restrict__ uT,
    const u16* __restrict__ bcT, const float* __restrict__ A_log,
    u16* __restrict__ pT, int layer)
{
    __shared__ float Ps[128 * 17], Qs[128 * 17];
    int slab = blockIdx.y;
    if (slab >> 1)
        scan_body<1>(deltaT, uT, bcT, A_log, pT, layer, slab, Ps, Qs);
    else
        scan_body<0>(deltaT, uT, bcT, A_log, pT, layer, slab, Ps, Qs);
}

// ---------------- gate: y = (p + Dskip*xc) * silu(z), pT -> token-major via LDS tile ----------------
__global__ __launch_bounds__(256) void gate_kernel(
    const u16* __restrict__ pT, const u16* __restrict__ xc,
    const u16* __restrict__ xz, const float* __restrict__ Dskip,
    u16* __restrict__ y, int layer)
{
    __shared__ float tile[32][33];
    int z = blockIdx.z, dir = z >> 1, b = z & 1;
    int d0 = blockIdx.x * 32, t0 = blockIdx.y * 32;
    int tx = threadIdx.x & 31, ty = threadIdx.x >> 5;
    #pragma unroll
    for (int k = 0; k < 4; ++k) {
        int d = d0 + ty + k * 8;
        tile[ty + k * 8][tx] = bf2f(pT[((size_t)(z * DI + d)) * LSEQ + t0 + tx]);
    }
    __syncthreads();
    #pragma unroll
    for (int k = 0; k < 4; ++k) {
        int t = t0 + ty + k * 8, d = d0 + tx;
        float p = tile[tx][ty + k * 8];
        float xcv = bf2f(xc[(size_t)((z << 10) + t) * DI + d]);
        float zv = bf2f(xz[(size_t)((b << 10) + t) * 2048 + dir * 1024 + 512 + d]);
        float dsk = Dskip[(layer * 2 + dir) * DI + d];
        float yv = (p + dsk * xcv) * (zv / (1.f + __expf(-zv)));
        y[(size_t)((z << 10) + t) * DI + d] = f2bf(yv);
    }
}

// ---------------- batchnorm stats over (B*L) per channel ----------------
__global__ __launch_bounds__(256) void bnstats_kernel(
    const u16* __restrict__ p0, const u16* __restrict__ p1, float* __restrict__ stats)
{
    int d = blockIdx.x, arr = blockIdx.y, tid = threadIdx.x;
    const u16* p = arr ? p1 : p0;
    float s = 0.f, q = 0.f;
    #pragma unroll
    for (int k = 0; k < 8; ++k) {
        float v = bf2f(p[(size_t)(tid + k * 256) * DMODEL + d]);
        s += v; q += v * v;
    }
    #pragma unroll
    for (int off = 1; off < 64; off <<= 1) { s += __shfl_xor(s, off); q += __shfl_xor(q, off); }
    __shared__ float ss[4], qs[4];
    if ((tid & 63) == 0) { ss[tid >> 6] = s; qs[tid >> 6] = q; }
    __syncthreads();
    if (tid == 0) {
        float S = ss[0] + ss[1] + ss[2] + ss[3];
        float Q2 = qs[0] + qs[1] + qs[2] + qs[3];
        float mean = S * (1.f / 2048.f);
        float var = Q2 * (1.f / 2048.f) - mean * mean;
        stats[(arr * DMODEL + d) * 2] = mean;
        stats[(arr * DMODEL + d) * 2 + 1] = rsqrtf(var + EPS);
    }
}

// ---------------- fused: BN-apply(f,bk) + residual + LN(f) + LN(bk) + sum ----------------
__global__ __launch_bounds__(256) void fuseln_kernel(
    const u16* __restrict__ x, const u16* __restrict__ outm, const float* __restrict__ stats,
    const float* __restrict__ bng, const float* __restrict__ bnb,
    const float* __restrict__ lng, const float* __restrict__ lnb, u16* __restrict__ ffin)
{
    int tok = blockIdx.x, d = threadIdx.x;
    float xv = bf2f(x[(size_t)tok * DMODEL + d]);
    float of = bf2f(outm[(size_t)tok * DMODEL + d]);
    float ob = bf2f(outm[(size_t)BTOK * DMODEL + (size_t)tok * DMODEL + d]);
    float vf = xv + (of - stats[d * 2]) * stats[d * 2 + 1] * bng[d] + bnb[d];
    float vb = xv + (ob - stats[(DMODEL + d) * 2]) * stats[(DMODEL + d) * 2 + 1] * bng[DMODEL + d] + bnb[DMODEL + d];
    float s0 = vf, s1 = vf * vf, s2 = vb, s3 = vb * vb;
    #pragma unroll
    for (int off = 1; off < 64; off <<= 1) {
        s0 += __shfl_xor(s0, off); s1 += __shfl_xor(s1, off);
        s2 += __shfl_xor(s2, off); s3 += __shfl_xor(s3, off);
    }
    __shared__ float sm[4][4];
    if ((d & 63) == 0) { sm[d >> 6][0] = s0; sm[d >> 6][1] = s1; sm[d >> 6][2] = s2; sm[d >> 6][3] = s3; }
    __syncthreads();
    s0 = sm[0][0] + sm[1][0] + sm[2][0] + sm[3][0];
    s1 = sm[0][1] + sm[1][1] + sm[2][1] + sm[3][1];
    s2 = sm[0][2] + sm[1][2] + sm[2][2] + sm[3][2];
    s3 = sm[0][3] + sm[1][3] + sm[2][3] + sm[3][3];
    float mf = s0 * (1.f / 256.f), vvf = s1 * (1.f / 256.f) - mf * mf;
    float mb = s2 * (1.f / 256.f), vvb = s3 * (1.f / 256.f) - mb * mb;
    float fl = (vf - mf) * rsqrtf(vvf + EPS) * lng[d] + lnb[d];
    float bl = (vb - mb) * rsqrtf(vvb + EPS) * lng[DMODEL + d] + lnb[DMODEL + d];
    ffin[(size_t)tok * DMODEL + d] = f2bf(fl + bl);
}

// ---------------- fused: BN-apply(ff) + residual add into x ----------------
__global__ __launch_bounds__(256) void bnadd_kernel(
    u16* __restrict__ x, const u16* __restrict__ ffo, const float* __restrict__ stats,
    const float* __restrict__ g, const float* __restrict__ b)
{
    int tok = blockIdx.x, d = threadIdx.x;
    size_t idx = (size_t)tok * DMODEL + d;
    float v = bf2f(x[idx]) + (bf2f(ffo[idx]) - stats[d * 2]) * stats[d * 2 + 1] * g[d] + b[d];
    x[idx] = f2bf(v);
}

// ---------------- host ----------------
extern "C" void kernel_launch(void* const* d_in, const int* in_sizes, int n_in,
                              void* d_out, int out_size, void* d_ws, size_t ws_size,
                              hipStream_t stream)
{
    const int*   ids     = (const int*)d_in[0];
    const float* emb     = (const float*)d_in[1];
    const float* pos     = (const float*)d_in[2];
    const float* Win     = (const float*)d_in[3];
    const float* conv_w  = (const float*)d_in[4];
    const float* conv_b  = (const float*)d_in[5];
    const float* Wx      = (const float*)d_in[6];
    const float* Wdt     = (const float*)d_in[7];
    const float* bdt     = (const float*)d_in[8];
    const float* A_log   = (const float*)d_in[9];
    const float* Dskip   = (const float*)d_in[10];
    const float* Wout    = (const float*)d_in[11];
    const float* bout    = (const float*)d_in[12];
    const float* bn_g    = (const float*)d_in[13];
    const float* bn_b    = (const float*)d_in[14];
    const float* ln_g    = (const float*)d_in[15];
    const float* ln_b    = (const float*)d_in[16];
    const float* ff_w1   = (const float*)d_in[17];
    const float* ff_b1   = (const float*)d_in[18];
    const float* ff_w2   = (const float*)d_in[19];
    const float* ff_b2   = (const float*)d_in[20];
    const float* final_w = (const float*)d_in[21];
    const float* final_b = (const float*)d_in[22];

    char* cur = (char*)d_ws;
    auto alloc = [&](size_t elems) {
        u16* p = (u16*)cur;
        cur += ((elems * 2 + 511) / 512) * 512;
        return p;
    };
    // transposed bf16 weights
    u16* winT  = alloc((size_t)NL * 2048 * 256);
    u16* wxT   = alloc((size_t)NL * 2 * 48 * 512);
    u16* wdtT  = alloc((size_t)NL * 2 * 512 * 16);
    u16* woutT = alloc((size_t)NL * 2 * 256 * 512);
    u16* fw1T  = alloc((size_t)NL * 1024 * 256);
    u16* fw2T  = alloc((size_t)NL * 256 * 1024);
    u16* finT  = alloc((size_t)1024 * 256);
    // activations (bf16)
    u16* xbuf   = alloc((size_t)BTOK * DMODEL);
    u16* xz     = alloc((size_t)BTOK * 2048);
    u16* xc     = alloc((size_t)2 * BTOK * DI);
    u16* xdb    = alloc((size_t)2 * BTOK * 48);
    u16* bcT    = alloc((size_t)4 * 32 * LSEQ);
    u16* deltaT = alloc((size_t)2 * BTOK * DI);
    u16* uT     = alloc((size_t)2 * BTOK * DI);
    u16* pT     = alloc((size_t)2 * BTOK * DI);
    u16* ybuf   = alloc((size_t)2 * BTOK * DI);
    u16* outm   = alloc((size_t)2 * BTOK * DMODEL);
    u16* ffin   = alloc((size_t)BTOK * DMODEL);
    u16* ffh    = alloc((size_t)BTOK * FF);
    u16* ffo    = alloc((size_t)BTOK * DMODEL);
    float* statsM = (float*)alloc(4096);          // 8KB: mamba stats + ff stats
    float* statsF = statsM + 1024;

    // ---- build transpose table ----
    TTable tt; int nm = 0, tiles = 0;
    auto addT = [&](const float* src, u16* dst, int rows, int cols) {
        int tc = (cols + 31) / 32, tr = (rows + 31) / 32;
        tt.m[nm] = {src, dst, rows, cols, tiles, tc};
        tiles += tc * tr; nm++;
    };
    for (int i = 0; i < NL; ++i) {
        for (int dir = 0; dir < 2; ++dir) {
            addT(Win  + (size_t)(i * 2 + dir) * 256 * 1024, winT  + (size_t)i * 2048 * 256 + (size_t)dir * 1024 * 256, 256, 1024);
            addT(Wx   + (size_t)(i * 2 + dir) * 512 * 48,   wxT   + (size_t)(i * 2 + dir) * 48 * 512,   512, 48);
            addT(Wdt  + (size_t)(i * 2 + dir) * 16 * 512,   wdtT  + (size_t)(i * 2 + dir) * 512 * 16,   16, 512);
            addT(Wout + (size_t)(i * 2 + dir) * 512 * 256,  woutT + (size_t)(i * 2 + dir) * 256 * 512,  512, 256);
        }
        addT(ff_w1 + (size_t)i * 256 * 1024, fw1T + (size_t)i * 1024 * 256, 256, 1024);
        addT(ff_w2 + (size_t)i * 1024 * 256, fw2T + (size_t)i * 256 * 1024, 1024, 256);
    }
    addT(final_w, finT, 256, 1024);
    tt.nmat = nm;
    transpose_kernel<<<tiles, 256, 0, stream>>>(tt);

    embed_kernel<<<BTOK, 256, 0, stream>>>(ids, emb, pos, xbuf);

    auto gemm = [&](const u16* A, int lda, size_t sA, const u16* Bt, int ldb, size_t sB,
                    const float* bias, size_t sBias, void* C, int ldc, size_t sC,
                    int M, int N, int K, int act, int nb, int outfp) {
        dim3 g((N + 63) / 64, M / 64, nb);
        gemm_kernel<<<g, 256, 0, stream>>>(A, lda, (unsigned long long)sA, Bt, ldb, (unsigned long long)sB,
                                           bias, (unsigned long long)sBias, C, ldc, (unsigned long long)sC,
                                           M, N, K, act, outfp);
    };
    // staged GEMMs: BN=128 (2x2 waves, 4x4 tiles) and BN=64 (4x1 waves, 2x4 tiles)
    auto sgemm128 = [&](const u16* A, int lda, const u16* Bt, int ldb, size_t sB,
                        const float* bias, size_t sBias, void* C, int ldc,
                        int N, int K, int act, int nb, int outfp) {
        dim3 g(N / 128, BTOK / 128, nb);
        sgemm_kernel<128, 2, 2, 4, 4><<<g, 256, 0, stream>>>(
            A, lda, 0ULL, Bt, ldb, (unsigned long long)sB, bias, (unsigned long long)sBias,
            C, ldc, 0ULL, K, act, outfp);
    };
    auto sgemm64 = [&](const u16* A, int lda, size_t sA, const u16* Bt, int ldb, size_t sB,
                       const float* bias, size_t sBias, void* C, int ldc, size_t sC,
                       int N, int K, int act, int nb, int outfp) {
        dim3 g(N / 64, BTOK / 128, nb);
        sgemm_kernel<64, 4, 1, 2, 4><<<g, 256, 0, stream>>>(
            A, lda, (unsigned long long)sA, Bt, ldb, (unsigned long long)sB,
            bias, (unsigned long long)sBias, C, ldc, (unsigned long long)sC, K, act, outfp);
    };

    for (int i = 0; i < NL; ++i) {
        // xz = x @ [Win_f | Win_b]  -> (BTOK, 2048)  [staged]
        sgemm128(xbuf, 256, winT + (size_t)i * 2048 * 256, 256, 0, nullptr, 0,
                 xz, 2048, 2048, 256, 0, 1, 0);
        // conv + silu (both dirs) -> xc token-major
        conv_kernel<<<(2 * BTOK * DI) / 256, 256, 0, stream>>>(xz, conv_w, conv_b, xc, i);
        // xdb = xc @ Wx  (batched over dir), N=48  [boundary kernel]
        gemm(xc, 512, (size_t)BTOK * 512, wxT + (size_t)i * 2 * 48 * 512, 512, 48 * 512,
             nullptr, 0, xdb, 48, (size_t)BTOK * 48, BTOK, 48, 512, 0, 2, 0);
        // Bm/Cm -> t-contiguous bcT
        bct_kernel<<<dim3(32, 4), 256, 0, stream>>>(xdb, bcT);
        // delta fused: softplus GEMM (K=16) + write deltaT, uT in (d,t) layout
        delta_fused_kernel<<<dim3(8, 32, 2), 256, 0, stream>>>(
            xdb, wdtT + (size_t)i * 2 * 512 * 16, bdt + (size_t)i * 2 * 512, xc, deltaT, uT, i);
        // selective scan -> pT (d,t layout)
        scan_kernel<<<dim3(512, 4), 128, 0, stream>>>(deltaT, uT, bcT, A_log, pT, i);
        // gate: y = (p + Dskip*xc) * silu(z), transposed back to token-major
        gate_kernel<<<dim3(DI / 32, LSEQ / 32, 4), 256, 0, stream>>>(pT, xc, xz, Dskip, ybuf, i);
        // out_m = y @ Wout + bout (batched)  [staged, BN=64]
        sgemm64(ybuf, 512, (size_t)BTOK * 512, woutT + (size_t)i * 2 * 256 * 512, 512, 256 * 512,
                bout + (size_t)i * 2 * 256, 256, outm, 256, (size_t)BTOK * 256, 256, 512, 0, 2, 0);
        // BN stats for both directions
        bnstats_kernel<<<dim3(256, 2), 256, 0, stream>>>(outm, outm + (size_t)BTOK * 256, statsM);
        // BN apply + residual + LN both + sum -> ffin
        fuseln_kernel<<<BTOK, 256, 0, stream>>>(xbuf, outm, statsM,
            bn_g + (size_t)i * 3 * 256, bn_b + (size_t)i * 3 * 256,
            ln_g + (size_t)i * 2 * 256, ln_b + (size_t)i * 2 * 256, ffin);
        // FF  [staged]
        sgemm128(ffin, 256, fw1T + (size_t)i * 1024 * 256, 256, 0,
                 ff_b1 + (size_t)i * 1024, 0, ffh, 1024, 1024, 256, 1, 1, 0);
        sgemm64(ffh, 1024, 0, fw2T + (size_t)i * 256 * 1024, 1024, 0,
                ff_b2 + (size_t)i * 256, 0, ffo, 256, 0, 256, 1024, 0, 1, 0);
        // BN stats ff + apply + residual
        bnstats_kernel<<<dim3(256, 1), 256, 0, stream>>>(ffo, ffo, statsF);
        bnadd_kernel<<<BTOK, 256, 0, stream>>>(xbuf, ffo, statsF,
            bn_g + (size_t)(i * 3 + 2) * 256, bn_b + (size_t)(i * 3 + 2) * 256);
    }
    // final logits = x @ final_w + final_b -> d_out (fp32)  [staged]
    sgemm128(xbuf, 256, finT, 256, 0, final_b, 0,
             d_out, 1024, 1024, 256, 0, 1, 1);
}

// Round 10
// 387.795 us; speedup vs baseline: 1.1213x; 1.1213x over previous
//
#include <hip/hip_runtime.h>

// ---------------- constants (problem shape) ----------------
#define NL 2
#define DMODEL 256
#define DI 512
#define FF 1024
#define VV 1024
#define LSEQ 1024
#define RR 16
#define NN 16
#define KCONV 4
#define BTOK 2048   // B * LSEQ
#define EPS 1e-5f

using short8 = __attribute__((ext_vector_type(8))) short;
using float4v = __attribute__((ext_vector_type(4))) float;
typedef unsigned short u16;

__device__ inline float bf2f(u16 u) {
    union { unsigned u; float f; } x; x.u = (unsigned)u << 16; return x.f;
}
__device__ inline u16 f2bf(float f) {
    union { float f; unsigned u; } x; x.f = f;
    unsigned r = x.u + 0x7fffu + ((x.u >> 16) & 1u);
    return (u16)(r >> 16);
}

#if __has_builtin(__builtin_amdgcn_exp2f)
#define EXP2(x) __builtin_amdgcn_exp2f(x)
#else
#define EXP2(x) exp2f(x)
#endif

// ---------------- transpose-all (fp32 weights -> bf16 N-major B^T) ----------------
struct TMat { const float* src; u16* dst; int rows, cols, tile0, tilecols; };
struct TTable { TMat m[24]; int nmat; };

__global__ __launch_bounds__(256) void transpose_kernel(TTable tt) {
    __shared__ u16 tile[32][33];
    int bx = blockIdx.x;
    int j = 0;
    for (int k = 1; k < tt.nmat; ++k) if (bx >= tt.m[k].tile0) j = k;
    TMat mm = tt.m[j];
    int lt = bx - mm.tile0;
    int r0 = (lt / mm.tilecols) * 32, c0 = (lt % mm.tilecols) * 32;
    int tx = threadIdx.x & 31, ty = threadIdx.x >> 5;
    #pragma unroll
    for (int k = 0; k < 4; ++k) {
        int r = r0 + ty + k * 8, c = c0 + tx;
        tile[ty + k * 8][tx] = (r < mm.rows && c < mm.cols) ? f2bf(mm.src[(size_t)r * mm.cols + c]) : (u16)0;
    }
    __syncthreads();
    #pragma unroll
    for (int k = 0; k < 4; ++k) {
        int c = c0 + ty + k * 8, r = r0 + tx;
        if (c < mm.cols && r < mm.rows) mm.dst[(size_t)c * mm.rows + r] = tile[tx][ty + k * 8];
    }
}

// ---------------- LDS-staged MFMA GEMM: C = act(A @ Bt^T + bias) [+ channel stats] ---
// BM=WR*RT*16, BN=WC*CT*16. Requires M%BM==0, N%BN==0, K%32==0.
// If stats!=nullptr, atomically accumulates per-channel (sum, sumsq) of the fp32
// output into stats[(z*statsStride + n)*2 + {0,1}].
template<int BM, int BN, int WR, int WC, int RT, int CT>
__global__ __launch_bounds__(256) void sgemm_kernel(
    const u16* __restrict__ A0, int lda, unsigned long long sA,
    const u16* __restrict__ B0, int ldb, unsigned long long sB,
    const float* __restrict__ bias0, unsigned long long sBias,
    void* __restrict__ C0, int ldc, unsigned long long sC,
    int K, int act, int outfp, float* __restrict__ stats, int statsStride)
{
    constexpr int BK = 32;
    __shared__ u16 As[BM * BK];
    __shared__ u16 Bs[BN * BK];
    const u16* A = A0 + (size_t)blockIdx.z * sA;
    const u16* Bt = B0 + (size_t)blockIdx.z * sB;
    const float* bias = bias0 ? (bias0 + (size_t)blockIdx.z * sBias) : nullptr;

    const int tid = threadIdx.x, w = tid >> 6, lane = tid & 63;
    const int row0 = blockIdx.y * BM, col0 = blockIdx.x * BN;
    const int wr = w / WC, wc = w % WC;
    const int mi = lane & 15, kq = lane >> 4;
    const int lr = lane >> 2, lc = (lane & 3) * 8;   // staging: lane -> row/col

    float4v acc[RT][CT];
    #pragma unroll
    for (int i = 0; i < RT; ++i)
        #pragma unroll
        for (int j = 0; j < CT; ++j) acc[i][j] = (float4v){0.f, 0.f, 0.f, 0.f};

    for (int kk = 0; kk < K; kk += BK) {
        __syncthreads();
        for (int i = w; i < BM / 16; i += 4) {
            const u16* g = A + (size_t)(row0 + i * 16 + lr) * lda + kk + lc;
            __builtin_amdgcn_global_load_lds(
                (const __attribute__((address_space(1))) void*)g,
                (__attribute__((address_space(3))) void*)(As + i * 16 * BK), 16, 0, 0);
        }
        for (int i = w; i < BN / 16; i += 4) {
            const u16* g = Bt + (size_t)(col0 + i * 16 + lr) * ldb + kk + lc;
            __builtin_amdgcn_global_load_lds(
                (const __attribute__((address_space(1))) void*)g,
                (__attribute__((address_space(3))) void*)(Bs + i * 16 * BK), 16, 0, 0);
        }
        __syncthreads();
        short8 af[RT], bf[CT];
        #pragma unroll
        for (int i = 0; i < RT; ++i)
            af[i] = *(const short8*)(As + (wr * RT * 16 + i * 16 + mi) * BK + kq * 8);
        #pragma unroll
        for (int j = 0; j < CT; ++j)
            bf[j] = *(const short8*)(Bs + (wc * CT * 16 + j * 16 + mi) * BK + kq * 8);
        #pragma unroll
        for (int i = 0; i < RT; ++i)
            #pragma unroll
            for (int j = 0; j < CT; ++j)
                acc[i][j] = __builtin_amdgcn_mfma_f32_16x16x32_bf16(af[i], bf[j], acc[i][j], 0, 0, 0);
    }

    #pragma unroll
    for (int j = 0; j < CT; ++j) {
        const int n = col0 + wc * CT * 16 + j * 16 + mi;
        const float bv = bias ? bias[n] : 0.f;
        float s = 0.f, q = 0.f;
        #pragma unroll
        for (int i = 0; i < RT; ++i) {
            #pragma unroll
            for (int r = 0; r < 4; ++r) {
                int m = row0 + wr * RT * 16 + i * 16 + kq * 4 + r;
                float v = acc[i][j][r] + bv;
                if (act == 1) v = fmaxf(v, 0.f);
                if (outfp)
                    ((float*)C0)[(size_t)blockIdx.z * sC + (size_t)m * ldc + n] = v;
                else
                    ((u16*)C0)[(size_t)blockIdx.z * sC + (size_t)m * ldc + n] = f2bf(v);
                s += v; q += v * v;
            }
        }
        if (stats) {
            s += __shfl_xor(s, 16); s += __shfl_xor(s, 32);
            q += __shfl_xor(q, 16); q += __shfl_xor(q, 32);
            if (lane < 16) {
                atomicAdd(&stats[(size_t)(blockIdx.z * statsStride + n) * 2], s);
                atomicAdd(&stats[(size_t)(blockIdx.z * statsStride + n) * 2 + 1], q);
            }
        }
    }
}

// ---------------- batched MFMA GEMM (boundary-safe; N=48 xdb) + fused bcT write -----
__global__ __launch_bounds__(256) void gemm_kernel(
    const u16* __restrict__ A0, int lda, unsigned long long sA,
    const u16* __restrict__ B0, int ldb, unsigned long long sB,
    const float* __restrict__ bias0, unsigned long long sBias,
    void* __restrict__ C0, int ldc, unsigned long long sC,
    int M, int N, int K, int act, int outfp, u16* __restrict__ bcT0)
{
    const u16* A = A0 + (size_t)blockIdx.z * sA;
    const u16* Bt = B0 + (size_t)blockIdx.z * sB;
    const float* bias = bias0 ? (bias0 + (size_t)blockIdx.z * sBias) : nullptr;

    int tid = threadIdx.x;
    int wv = tid >> 6, lane = tid & 63;
    int row0 = blockIdx.y * 64 + (wv >> 1) * 32;
    int col0 = blockIdx.x * 64 + (wv & 1) * 32;
    int mi = lane & 15, kq = lane >> 4;

    float4v acc[2][2];
    #pragma unroll
    for (int a = 0; a < 2; ++a)
        #pragma unroll
        for (int b = 0; b < 2; ++b) acc[a][b] = (float4v){0.f, 0.f, 0.f, 0.f};
    const short8 zer = {0, 0, 0, 0, 0, 0, 0, 0};

    for (int kk = 0; kk < K; kk += 32) {
        int k = kk + kq * 8;
        bool kv = (k < K);
        short8 af[2], bf[2];
        #pragma unroll
        for (int rt = 0; rt < 2; ++rt) {
            int r = row0 + rt * 16 + mi;
            af[rt] = kv ? *(const short8*)(A + (size_t)r * lda + k) : zer;
        }
        #pragma unroll
        for (int ct = 0; ct < 2; ++ct) {
            int n = col0 + ct * 16 + mi;
            bf[ct] = (kv && n < N) ? *(const short8*)(Bt + (size_t)n * ldb + k) : zer;
        }
        #pragma unroll
        for (int rt = 0; rt < 2; ++rt)
            #pragma unroll
            for (int ct = 0; ct < 2; ++ct)
                acc[rt][ct] = __builtin_amdgcn_mfma_f32_16x16x32_bf16(af[rt], bf[ct], acc[rt][ct], 0, 0, 0);
    }

    #pragma unroll
    for (int rt = 0; rt < 2; ++rt)
        #pragma unroll
        for (int ct = 0; ct < 2; ++ct) {
            int n = col0 + ct * 16 + mi;
            if (n >= N) continue;
            float bv = bias ? bias[n] : 0.f;
            #pragma unroll
            for (int r = 0; r < 4; ++r) {
                int m = row0 + rt * 16 + kq * 4 + r;
                float v = acc[rt][ct][r] + bv;
                if (act == 1) v = fmaxf(v, 0.f);
                u16 hv = f2bf(v);
                if (outfp)
                    ((float*)C0)[(size_t)blockIdx.z * sC + (size_t)m * ldc + n] = v;
                else
                    ((u16*)C0)[(size_t)blockIdx.z * sC + (size_t)m * ldc + n] = hv;
                if (bcT0 && n >= 16) {
                    int bb = m >> 10, t = m & 1023;
                    bcT0[((size_t)((blockIdx.z * 2 + bb) * 32 + (n - 16))) * LSEQ + t] = hv;
                }
            }
        }
}

// ---------------- fused delta GEMM (K=16): delta = softplus(xdb[:, :16] @ Wdt + bdt) ----------------
__global__ __launch_bounds__(256) void delta_fused_kernel(
    const u16* __restrict__ xdb, const u16* __restrict__ wdtT,
    const float* __restrict__ bdt, const u16* __restrict__ xc,
    u16* __restrict__ deltaT, u16* __restrict__ uT, int layer)
{
    int z = blockIdx.z;   // dir
    const u16* A = xdb + (size_t)z * BTOK * 48;
    const u16* Bt = wdtT + (size_t)z * 512 * 16;
    const float* bias = bdt + (size_t)z * 512;

    int tid = threadIdx.x;
    int wv = tid >> 6, lane = tid & 63;
    int row0 = blockIdx.y * 64 + (wv >> 1) * 32;
    int col0 = blockIdx.x * 64 + (wv & 1) * 32;
    int mi = lane & 15, kq = lane >> 4;

    float4v acc[2][2];
    #pragma unroll
    for (int a = 0; a < 2; ++a)
        #pragma unroll
        for (int b = 0; b < 2; ++b) acc[a][b] = (float4v){0.f, 0.f, 0.f, 0.f};
    const short8 zer = {0, 0, 0, 0, 0, 0, 0, 0};

    int k = kq * 8;
    bool kv = (k < 16);
    short8 af[2], bf[2];
    #pragma unroll
    for (int rt = 0; rt < 2; ++rt) {
        int r = row0 + rt * 16 + mi;
        af[rt] = kv ? *(const short8*)(A + (size_t)r * 48 + k) : zer;
    }
    #pragma unroll
    for (int ct = 0; ct < 2; ++ct) {
        int n = col0 + ct * 16 + mi;
        bf[ct] = kv ? *(const short8*)(Bt + (size_t)n * 16 + k) : zer;
    }
    #pragma unroll
    for (int rt = 0; rt < 2; ++rt)
        #pragma unroll
        for (int ct = 0; ct < 2; ++ct)
            acc[rt][ct] = __builtin_amdgcn_mfma_f32_16x16x32_bf16(af[rt], bf[ct], acc[rt][ct], 0, 0, 0);

    #pragma unroll
    for (int rt = 0; rt < 2; ++rt)
        #pragma unroll
        for (int ct = 0; ct < 2; ++ct) {
            int n = col0 + ct * 16 + mi;
            float bv = bias[n];
            #pragma unroll
            for (int r = 0; r < 4; ++r) {
                int m = row0 + rt * 16 + kq * 4 + r;
                float v = acc[rt][ct][r] + bv;
                v = (v > 20.f) ? v : logf(1.f + __expf(v));   // softplus
                float xcv = bf2f(xc[((size_t)z * BTOK + m) * DI + n]);
                int b = m >> 10, t = m & 1023;
                size_t off = ((size_t)((z * 2 + b) * DI + n)) * LSEQ + t;
                deltaT[off] = f2bf(v);
                uT[off] = f2bf(v * xcv);
            }
        }
}

// ---------------- embedding ----------------
__global__ __launch_bounds__(256) void embed_kernel(
    const int* __restrict__ ids, const float* __restrict__ emb,
    const float* __restrict__ pos, u16* __restrict__ x)
{
    int tok = blockIdx.x, d = threadIdx.x;
    int id = ids[tok];
    float v = emb[(size_t)id * DMODEL + d] * 16.0f + pos[(size_t)(tok & (LSEQ - 1)) * DMODEL + d];
    x[(size_t)tok * DMODEL + d] = f2bf(v);
}

// ---------------- depthwise causal / anti-causal conv + SiLU ----------------
__global__ __launch_bounds__(256) void conv_kernel(
    const u16* __restrict__ xz, const float* __restrict__ conv_w,
    const float* __restrict__ conv_b, u16* __restrict__ xc, int layer)
{
    unsigned g = blockIdx.x * 256u + threadIdx.x;   // 2*2*1024*512 total
    int d = g & 511;
    int t = (g >> 9) & 1023;
    int b = (g >> 19) & 1;
    int dir = g >> 20;
    int wbase = ((layer * 2 + dir) * DI + d);
    float acc = conv_b[wbase];
    int colbase = dir * 1024 + d;
    #pragma unroll
    for (int k = 0; k < KCONV; ++k) {
        int ts = dir ? (t + 3 - k) : (t - 3 + k);
        if (ts >= 0 && ts < LSEQ)
            acc += conv_w[wbase * KCONV + k] * bf2f(xz[(size_t)((b << 10) + ts) * 2048 + colbase]);
    }
    float v = acc / (1.f + __expf(-acc));   // silu
    xc[(size_t)(((dir * 2 + b) << 10) + t) * DI + d] = f2bf(v);
}

// ---------------- selective scan: n-outer streaming, coalesced bcT, K-S stitch ----
template<int DIR>
__device__ __forceinline__ void scan_body(
    const u16* __restrict__ deltaT, const u16* __restrict__ uT,
    const u16* __restrict__ bcT, const float* __restrict__ A_log,
    u16* __restrict__ pT, int layer, int slab,
    float* Ps, float* Qs)
{
    const int c = threadIdx.x;   // chunk 0..127
    const int d = blockIdx.x;

    float a2[16];
    const float* al = A_log + (size_t)(((layer * 2 + DIR) * DI + d) * NN);
    #pragma unroll
    for (int n = 0; n < 16; ++n) a2[n] = -__expf(al[n]) * 1.44269504f;   // a*log2(e)

    const size_t tb = ((size_t)(slab * DI + d)) * LSEQ;
    const size_t bcb = (size_t)slab * 32 * LSEQ;
    const int T0 = DIR ? (1016 - 8 * c) : (8 * c);

    short8 dlv = *(const short8*)(deltaT + tb + T0);
    short8 uvv = *(const short8*)(uT + tb + T0);
    float dls[8], uvs[8];
    #pragma unroll
    for (int s = 0; s < 8; ++s) {
        const int idx = DIR ? 7 - s : s;
        dls[s] = bf2f((u16)dlv[idx]);
        uvs[s] = bf2f((u16)uvv[idx]);
    }

    const int base = c * 17;
    #pragma unroll
    for (int n = 0; n < 16; ++n) {
        short8 B8 = *(const short8*)(bcT + bcb + (size_t)n * LSEQ + T0);
        float P = 1.f, Q = 0.f;
        #pragma unroll
        for (int s = 0; s < 8; ++s) {
            const int idx = DIR ? 7 - s : s;
            float dA = EXP2(dls[s] * a2[n]);
            Q = Q * dA + uvs[s] * bf2f((u16)B8[idx]);
            P *= dA;
        }
        Ps[base + n] = P;
        Qs[base + n] = Q;
    }
    __syncthreads();

    for (int off = 1; off < 128; off <<= 1) {
        float np[16], nq[16];
        const bool act = (c >= off);
        if (act) {
            const int nb = (c - off) * 17;
            #pragma unroll
            for (int n = 0; n < 16; ++n) { np[n] = Ps[nb + n]; nq[n] = Qs[nb + n]; }
        }
        __syncthreads();
        if (act) {
            #pragma unroll
            for (int n = 0; n < 16; ++n) {
                float p = Ps[base + n], q = Qs[base + n];
                Qs[base + n] = fmaf(p, nq[n], q);
                Ps[base + n] = p * np[n];
            }
        }
        __syncthreads();
    }

    float pacc[8];
    #pragma unroll
    for (int s = 0; s < 8; ++s) pacc[s] = 0.f;
    const int hb = (c - 1) * 17;
    #pragma unroll
    for (int n = 0; n < 16; ++n) {
        short8 B8 = *(const short8*)(bcT + bcb + (size_t)n * LSEQ + T0);
        short8 C8 = *(const short8*)(bcT + bcb + (size_t)(16 + n) * LSEQ + T0);
        float h = (c == 0) ? 0.f : Qs[hb + n];
        #pragma unroll
        for (int s = 0; s < 8; ++s) {
            const int idx = DIR ? 7 - s : s;
            float dA = EXP2(dls[s] * a2[n]);
            h = h * dA + uvs[s] * bf2f((u16)B8[idx]);
            pacc[s] = fmaf(h, bf2f((u16)C8[idx]), pacc[s]);
        }
    }
    short8 pk;
    #pragma unroll
    for (int s = 0; s < 8; ++s) {
        const int idx = DIR ? 7 - s : s;
        pk[idx] = (short)f2bf(pacc[s]);
    }
    *(short8*)(pT + tb + T0) = pk;
}

__global__ __launch_bounds__(128) void scan_kernel(
    const u16* __restrict__ deltaT, const u16* __restrict__ uT,
    const u16* __restrict__ bcT, const float* __restrict__ A_log,
    u16* __restrict__ pT, int layer)
{
    __shared__ float Ps[128 * 17], Qs[128 * 17];
    int slab = blockIdx.y;
    if (slab >> 1)
        scan_body<1>(deltaT, uT, bcT, A_log, pT, layer, slab, Ps, Qs);
    else
        scan_body<0>(deltaT, uT, bcT, A_log, pT, layer, slab, Ps, Qs);
}

// ---------------- gate: y = (p + Dskip*xc) * silu(z); also zeroes statsM ----------------
__global__ __launch_bounds__(256) void gate_kernel(
    const u16* __restrict__ pT, const u16* __restrict__ xc,
    const u16* __restrict__ xz, const float* __restrict__ Dskip,
    u16* __restrict__ y, float* __restrict__ statsM, int layer)
{
    if (blockIdx.x == 0 && blockIdx.y == 0 && blockIdx.z == 0) {
        for (int k = threadIdx.x; k < 2048; k += 256) statsM[k] = 0.f;
    }
    __shared__ float tile[32][33];
    int z = blockIdx.z, dir = z >> 1, b = z & 1;
    int d0 = blockIdx.x * 32, t0 = blockIdx.y * 32;
    int tx = threadIdx.x & 31, ty = threadIdx.x >> 5;
    #pragma unroll
    for (int k = 0; k < 4; ++k) {
        int d = d0 + ty + k * 8;
        tile[ty + k * 8][tx] = bf2f(pT[((size_t)(z * DI + d)) * LSEQ + t0 + tx]);
    }
    __syncthreads();
    #pragma unroll
    for (int k = 0; k < 4; ++k) {
        int t = t0 + ty + k * 8, d = d0 + tx;
        float p = tile[tx][ty + k * 8];
        float xcv = bf2f(xc[(size_t)((z << 10) + t) * DI + d]);
        float zv = bf2f(xz[(size_t)((b << 10) + t) * 2048 + dir * 1024 + 512 + d]);
        float dsk = Dskip[(layer * 2 + dir) * DI + d];
        float yv = (p + dsk * xcv) * (zv / (1.f + __expf(-zv)));
        y[(size_t)((z << 10) + t) * DI + d] = f2bf(yv);
    }
}

// ------- fused: BN-apply(f,bk from raw sums) + residual + LN both + sum; zero statsF -------
__global__ __launch_bounds__(256) void fuseln_kernel(
    const u16* __restrict__ x, const u16* __restrict__ outm, const float* __restrict__ stats,
    const float* __restrict__ bng, const float* __restrict__ bnb,
    const float* __restrict__ lng, const float* __restrict__ lnb,
    u16* __restrict__ ffin, float* __restrict__ statsF)
{
    int tok = blockIdx.x, d = threadIdx.x;
    if (tok == 0) { for (int k = d; k < 512; k += 256) statsF[k] = 0.f; }
    float xv = bf2f(x[(size_t)tok * DMODEL + d]);
    float of = bf2f(outm[(size_t)tok * DMODEL + d]);
    float ob = bf2f(outm[(size_t)BTOK * DMODEL + (size_t)tok * DMODEL + d]);
    float mf0 = stats[d * 2] * (1.f / 2048.f);
    float rf0 = rsqrtf(stats[d * 2 + 1] * (1.f / 2048.f) - mf0 * mf0 + EPS);
    float mb0 = stats[(DMODEL + d) * 2] * (1.f / 2048.f);
    float rb0 = rsqrtf(stats[(DMODEL + d) * 2 + 1] * (1.f / 2048.f) - mb0 * mb0 + EPS);
    float vf = xv + (of - mf0) * rf0 * bng[d] + bnb[d];
    float vb = xv + (ob - mb0) * rb0 * bng[DMODEL + d] + bnb[DMODEL + d];
    float s0 = vf, s1 = vf * vf, s2 = vb, s3 = vb * vb;
    #pragma unroll
    for (int off = 1; off < 64; off <<= 1) {
        s0 += __shfl_xor(s0, off); s1 += __shfl_xor(s1, off);
        s2 += __shfl_xor(s2, off); s3 += __shfl_xor(s3, off);
    }
    __shared__ float sm[4][4];
    if ((d & 63) == 0) { sm[d >> 6][0] = s0; sm[d >> 6][1] = s1; sm[d >> 6][2] = s2; sm[d >> 6][3] = s3; }
    __syncthreads();
    s0 = sm[0][0] + sm[1][0] + sm[2][0] + sm[3][0];
    s1 = sm[0][1] + sm[1][1] + sm[2][1] + sm[3][1];
    s2 = sm[0][2] + sm[1][2] + sm[2][2] + sm[3][2];
    s3 = sm[0][3] + sm[1][3] + sm[2][3] + sm[3][3];
    float mf = s0 * (1.f / 256.f), vvf = s1 * (1.f / 256.f) - mf * mf;
    float mb = s2 * (1.f / 256.f), vvb = s3 * (1.f / 256.f) - mb * mb;
    float fl = (vf - mf) * rsqrtf(vvf + EPS) * lng[d] + lnb[d];
    float bl = (vb - mb) * rsqrtf(vvb + EPS) * lng[DMODEL + d] + lnb[DMODEL + d];
    ffin[(size_t)tok * DMODEL + d] = f2bf(fl + bl);
}

// ---------------- fused: BN-apply(ff, raw sums) + residual add into x ----------------
__global__ __launch_bounds__(256) void bnadd_kernel(
    u16* __restrict__ x, const u16* __restrict__ ffo, const float* __restrict__ stats,
    const float* __restrict__ g, const float* __restrict__ b)
{
    int tok = blockIdx.x, d = threadIdx.x;
    size_t idx = (size_t)tok * DMODEL + d;
    float mean = stats[d * 2] * (1.f / 2048.f);
    float rs = rsqrtf(stats[d * 2 + 1] * (1.f / 2048.f) - mean * mean + EPS);
    float v = bf2f(x[idx]) + (bf2f(ffo[idx]) - mean) * rs * g[d] + b[d];
    x[idx] = f2bf(v);
}

// ---------------- host ----------------
extern "C" void kernel_launch(void* const* d_in, const int* in_sizes, int n_in,
                              void* d_out, int out_size, void* d_ws, size_t ws_size,
                              hipStream_t stream)
{
    const int*   ids     = (const int*)d_in[0];
    const float* emb     = (const float*)d_in[1];
    const float* pos     = (const float*)d_in[2];
    const float* Win     = (const float*)d_in[3];
    const float* conv_w  = (const float*)d_in[4];
    const float* conv_b  = (const float*)d_in[5];
    const float* Wx      = (const float*)d_in[6];
    const float* Wdt     = (const float*)d_in[7];
    const float* bdt     = (const float*)d_in[8];
    const float* A_log   = (const float*)d_in[9];
    const float* Dskip   = (const float*)d_in[10];
    const float* Wout    = (const float*)d_in[11];
    const float* bout    = (const float*)d_in[12];
    const float* bn_g    = (const float*)d_in[13];
    const float* bn_b    = (const float*)d_in[14];
    const float* ln_g    = (const float*)d_in[15];
    const float* ln_b    = (const float*)d_in[16];
    const float* ff_w1   = (const float*)d_in[17];
    const float* ff_b1   = (const float*)d_in[18];
    const float* ff_w2   = (const float*)d_in[19];
    const float* ff_b2   = (const float*)d_in[20];
    const float* final_w = (const float*)d_in[21];
    const float* final_b = (const float*)d_in[22];

    char* cur = (char*)d_ws;
    auto alloc = [&](size_t elems) {
        u16* p = (u16*)cur;
        cur += ((elems * 2 + 511) / 512) * 512;
        return p;
    };
    // transposed bf16 weights
    u16* winT  = alloc((size_t)NL * 2048 * 256);
    u16* wxT   = alloc((size_t)NL * 2 * 48 * 512);
    u16* wdtT  = alloc((size_t)NL * 2 * 512 * 16);
    u16* woutT = alloc((size_t)NL * 2 * 256 * 512);
    u16* fw1T  = alloc((size_t)NL * 1024 * 256);
    u16* fw2T  = alloc((size_t)NL * 256 * 1024);
    u16* finT  = alloc((size_t)1024 * 256);
    // activations (bf16)
    u16* xbuf   = alloc((size_t)BTOK * DMODEL);
    u16* xz     = alloc((size_t)BTOK * 2048);
    u16* xc     = alloc((size_t)2 * BTOK * DI);
    u16* xdb    = alloc((size_t)2 * BTOK * 48);
    u16* bcT    = alloc((size_t)4 * 32 * LSEQ);
    u16* deltaT = alloc((size_t)2 * BTOK * DI);
    u16* uT     = alloc((size_t)2 * BTOK * DI);
    u16* pT     = alloc((size_t)2 * BTOK * DI);
    u16* ybuf   = alloc((size_t)2 * BTOK * DI);
    u16* outm   = alloc((size_t)2 * BTOK * DMODEL);
    u16* ffin   = alloc((size_t)BTOK * DMODEL);
    u16* ffh    = alloc((size_t)BTOK * FF);
    u16* ffo    = alloc((size_t)BTOK * DMODEL);
    float* statsM = (float*)alloc(4096);          // raw (sum,sumsq): 1024 pairs + 256 pairs
    float* statsF = statsM + 2048;

    // ---- build transpose table ----
    TTable tt; int nm = 0, tiles = 0;
    auto addT = [&](const float* src, u16* dst, int rows, int cols) {
        int tc = (cols + 31) / 32, tr = (rows + 31) / 32;
        tt.m[nm] = {src, dst, rows, cols, tiles, tc};
        tiles += tc * tr; nm++;
    };
    for (int i = 0; i < NL; ++i) {
        for (int dir = 0; dir < 2; ++dir) {
            addT(Win  + (size_t)(i * 2 + dir) * 256 * 1024, winT  + (size_t)i * 2048 * 256 + (size_t)dir * 1024 * 256, 256, 1024);
            addT(Wx   + (size_t)(i * 2 + dir) * 512 * 48,   wxT   + (size_t)(i * 2 + dir) * 48 * 512,   512, 48);
            addT(Wdt  + (size_t)(i * 2 + dir) * 16 * 512,   wdtT  + (size_t)(i * 2 + dir) * 512 * 16,   16, 512);
            addT(Wout + (size_t)(i * 2 + dir) * 512 * 256,  woutT + (size_t)(i * 2 + dir) * 256 * 512,  512, 256);
        }
        addT(ff_w1 + (size_t)i * 256 * 1024, fw1T + (size_t)i * 1024 * 256, 256, 1024);
        addT(ff_w2 + (size_t)i * 1024 * 256, fw2T + (size_t)i * 256 * 1024, 1024, 256);
    }
    addT(final_w, finT, 256, 1024);
    tt.nmat = nm;
    transpose_kernel<<<tiles, 256, 0, stream>>>(tt);

    embed_kernel<<<BTOK, 256, 0, stream>>>(ids, emb, pos, xbuf);

    for (int i = 0; i < NL; ++i) {
        // xz = x @ [Win_f | Win_b]  -> (BTOK, 2048)   [128x128, grid 256]
        sgemm_kernel<128, 128, 2, 2, 4, 4><<<dim3(16, 16), 256, 0, stream>>>(
            xbuf, 256, 0ULL, winT + (size_t)i * 2048 * 256, 256, 0ULL, nullptr, 0ULL,
            xz, 2048, 0ULL, 256, 0, 0, nullptr, 0);
        // conv + silu (both dirs) -> xc token-major
        conv_kernel<<<(2 * BTOK * DI) / 256, 256, 0, stream>>>(xz, conv_w, conv_b, xc, i);
        // xdb = xc @ Wx (batched, N=48) + fused bcT transpose write
        gemm_kernel<<<dim3(1, 32, 2), 256, 0, stream>>>(
            xc, 512, (unsigned long long)((size_t)BTOK * 512),
            wxT + (size_t)i * 2 * 48 * 512, 512, 48ULL * 512, nullptr, 0ULL,
            xdb, 48, (unsigned long long)((size_t)BTOK * 48), BTOK, 48, 512, 0, 0, bcT);
        // delta fused: softplus GEMM (K=16) + write deltaT, uT in (d,t) layout
        delta_fused_kernel<<<dim3(8, 32, 2), 256, 0, stream>>>(
            xdb, wdtT + (size_t)i * 2 * 512 * 16, bdt + (size_t)i * 2 * 512, xc, deltaT, uT, i);
        // selective scan -> pT (d,t layout)
        scan_kernel<<<dim3(512, 4), 128, 0, stream>>>(deltaT, uT, bcT, A_log, pT, i);
        // gate (+ zero statsM)
        gate_kernel<<<dim3(DI / 32, LSEQ / 32, 4), 256, 0, stream>>>(pT, xc, xz, Dskip, ybuf, statsM, i);
        // out_m = y @ Wout + bout (batched) [64x64, grid 256] + channel stats atomics
        sgemm_kernel<64, 64, 2, 2, 2, 2><<<dim3(4, 32, 2), 256, 0, stream>>>(
            ybuf, 512, (unsigned long long)((size_t)BTOK * 512),
            woutT + (size_t)i * 2 * 256 * 512, 512, 256ULL * 512,
            bout + (size_t)i * 2 * 256, 256ULL,
            outm, 256, (unsigned long long)((size_t)BTOK * 256), 512, 0, 0, statsM, 256);
        // BN apply + residual + LN both + sum -> ffin (+ zero statsF)
        fuseln_kernel<<<BTOK, 256, 0, stream>>>(xbuf, outm, statsM,
            bn_g + (size_t)i * 3 * 256, bn_b + (size_t)i * 3 * 256,
            ln_g + (size_t)i * 2 * 256, ln_b + (size_t)i * 2 * 256, ffin, statsF);
        // FF1 [128x64, grid 256]
        sgemm_kernel<128, 64, 4, 1, 2, 4><<<dim3(16, 16), 256, 0, stream>>>(
            ffin, 256, 0ULL, fw1T + (size_t)i * 1024 * 256, 256, 0ULL,
            ff_b1 + (size_t)i * 1024, 0ULL, ffh, 1024, 0ULL, 256, 1, 0, nullptr, 0);
        // FF2 [64x64, grid 128] + channel stats atomics
        sgemm_kernel<64, 64, 2, 2, 2, 2><<<dim3(4, 32), 256, 0, stream>>>(
            ffh, 1024, 0ULL, fw2T + (size_t)i * 256 * 1024, 1024, 0ULL,
            ff_b2 + (size_t)i * 256, 0ULL, ffo, 256, 0ULL, 1024, 0, 0, statsF, 0);
        // BN apply + residual
        bnadd_kernel<<<BTOK, 256, 0, stream>>>(xbuf, ffo, statsF,
            bn_g + (size_t)(i * 3 + 2) * 256, bn_b + (size_t)(i * 3 + 2) * 256);
    }
    // final logits = x @ final_w + final_b -> d_out (fp32) [128x64, grid 256]
    sgemm_kernel<128, 64, 4, 1, 2, 4><<<dim3(16, 16), 256, 0, stream>>>(
        xbuf, 256, 0ULL, finT, 256, 0ULL, final_b, 0ULL,
        d_out, 1024, 0ULL, 256, 0, 1, nullptr, 0);
}